// Round 10
// baseline (409.240 us; speedup 1.0000x reference)
//
#include <hip/hip_runtime.h>
#include <math.h>

typedef __attribute__((ext_vector_type(8))) short short8;
typedef __attribute__((ext_vector_type(4))) float f32x4;

#define INF 3.0e38f
#define BN_EPS 1e-5f

// ---- grids for 3-NN: 1D x-buckets (phase A) + 2D xy-buckets (phase B) ---
#define NB 1024            // x-buckets per batch (phase A)
#define XMIN (-64.0f)
#define INVW 8.0f          // 1/0.125
#define PA 192             // phase-A x-nearest per query (24 per lane)
#define NG 64              // 2D grid dim per axis
#define NG2 4096           // NG*NG
#define GIW 0.5f           // 1 / 2.0 bucket width

__device__ __forceinline__ unsigned short f2bf(float x) {
    union { float f; unsigned u; } v; v.f = x;
    unsigned r = v.u + 0x7FFF + ((v.u >> 16) & 1);   // RNE
    return (unsigned short)(r >> 16);
}
__device__ __forceinline__ float bf2f(unsigned short u) {
    return __uint_as_float(((unsigned)u) << 16);
}
__device__ __forceinline__ unsigned long long shflx_u64(unsigned long long v, int m) {
    int lo = __shfl_xor((int)(unsigned)(v & 0xFFFFFFFFULL), m, 64);
    int hi = __shfl_xor((int)(unsigned)(v >> 32), m, 64);
    return ((unsigned long long)(unsigned)hi << 32) | (unsigned)lo;
}

// ------------------------------------------------- grid: fused histogram --
// known -> kc1 (1D x) + kc2 (2D xy); unknown -> qc2 (2D xy).
__global__ __launch_bounds__(256) void hist3_kernel(
    const float* __restrict__ kn, const int* __restrict__ kcnt, int M,
    const float* __restrict__ un, const int* __restrict__ ucnt, int N,
    int B, int* __restrict__ kc1, int* __restrict__ kc2, int* __restrict__ qc2)
{
    int j = blockIdx.x * 256 + threadIdx.x;
    if (j < M) {
        int cum = 0, bb = 0;
        for (int i = 0; i < B; i++) { int c = kcnt[i]; if (j >= cum) bb = i; cum += c; }
        float x = kn[j * 3], y = kn[j * 3 + 1];
        int b1 = min(max((int)((x - XMIN) * INVW), 0), NB - 1);
        atomicAdd(&kc1[bb * NB + b1], 1);
        int bx = min(max((int)((x - XMIN) * GIW), 0), NG - 1);
        int by = min(max((int)((y - XMIN) * GIW), 0), NG - 1);
        atomicAdd(&kc2[bb * NG2 + by * NG + bx], 1);
    } else {
        int idx = j - M; if (idx >= N) return;
        int cum = 0, bb = 0;
        for (int i = 0; i < B; i++) { int c = ucnt[i]; if (idx >= cum) bb = i; cum += c; }
        float x = un[idx * 3], y = un[idx * 3 + 1];
        int bx = min(max((int)((x - XMIN) * GIW), 0), NG - 1);
        int by = min(max((int)((y - XMIN) * GIW), 0), NG - 1);
        atomicAdd(&qc2[bb * NG2 + by * NG + bx], 1);
    }
}

// -------------------- grid: 3 exclusive scans (kc1:T1, kc2:T2, qc2:T2) ----
__global__ __launch_bounds__(1024) void scan3_kernel(
    const int* __restrict__ kc1, int* __restrict__ kbs1, int* __restrict__ kcur1,
    const int* __restrict__ kc2, int* __restrict__ kbs2, int* __restrict__ kcur2,
    const int* __restrict__ qc2, int* __restrict__ qbs2, int* __restrict__ qcur2,
    int T1, int T2)
{
    __shared__ int ts[1024];
    const int* cnt; int* bs; int* cur; int T;
    if (blockIdx.x == 0)      { cnt = kc1; bs = kbs1; cur = kcur1; T = T1; }
    else if (blockIdx.x == 1) { cnt = kc2; bs = kbs2; cur = kcur2; T = T2; }
    else                      { cnt = qc2; bs = qbs2; cur = qcur2; T = T2; }
    int tid = threadIdx.x;
    int v[16]; int s = 0;
#pragma unroll
    for (int c = 0; c < 16; c++) {
        int idx = tid * 16 + c;
        int val = (idx < T) ? cnt[idx] : 0;
        v[c] = val; s += val;
    }
    ts[tid] = s;
    __syncthreads();
    for (int off = 1; off < 1024; off <<= 1) {
        int t = (tid >= off) ? ts[tid - off] : 0;
        __syncthreads();
        ts[tid] += t;
        __syncthreads();
    }
    int ex = ts[tid] - s;
#pragma unroll
    for (int c = 0; c < 16; c++) {
        int idx = tid * 16 + c;
        if (idx < T) { bs[idx] = ex; cur[idx] = ex; }
        ex += v[c];
    }
    if (tid == 1023) bs[T] = ts[1023];
}

// --------------------------------------------------- grid: fused scatter --
__global__ __launch_bounds__(256) void scatter3_kernel(
    const float* __restrict__ kn, const int* __restrict__ kcnt, int M,
    const float* __restrict__ un, const int* __restrict__ ucnt, int N, int B,
    int* __restrict__ kcur1, float4* __restrict__ kscat1,
    int* __restrict__ kcur2, float4* __restrict__ kscat2,
    int* __restrict__ qcur2, float4* __restrict__ qscat)
{
    int j = blockIdx.x * 256 + threadIdx.x;
    if (j < M) {
        int cum = 0, bb = 0;
        for (int i = 0; i < B; i++) { int c = kcnt[i]; if (j >= cum) bb = i; cum += c; }
        float x = kn[j * 3], y = kn[j * 3 + 1], z = kn[j * 3 + 2];
        float4 f = make_float4(x, y, z, __int_as_float(j));
        int b1 = min(max((int)((x - XMIN) * INVW), 0), NB - 1);
        int p1 = atomicAdd(&kcur1[bb * NB + b1], 1);
        kscat1[p1] = f;
        int bx = min(max((int)((x - XMIN) * GIW), 0), NG - 1);
        int by = min(max((int)((y - XMIN) * GIW), 0), NG - 1);
        int p2 = atomicAdd(&kcur2[bb * NG2 + by * NG + bx], 1);
        kscat2[p2] = f;
    } else {
        int idx = j - M; if (idx >= N) return;
        int cum = 0, bb = 0;
        for (int i = 0; i < B; i++) { int c = ucnt[i]; if (idx >= cum) bb = i; cum += c; }
        float x = un[idx * 3], y = un[idx * 3 + 1], z = un[idx * 3 + 2];
        int bx = min(max((int)((x - XMIN) * GIW), 0), NG - 1);
        int by = min(max((int)((y - XMIN) * GIW), 0), NG - 1);
        int p = atomicAdd(&qcur2[bb * NG2 + by * NG + bx], 1);
        qscat[p] = make_float4(x, y, z, __int_as_float(idx));
    }
}

// ---------------------------------------------------------------- 3-NN ----
// Wave = 8 queries x 8 private lanes (lane = r8*8 + qi); queries 2D-sorted
// so a wave's 8 queries share one (x,y) box (L1-hot). No LDS/barriers.
// Phase A (1D): value-only top-3 over own 24 of the query's 192 x-nearest
//   (kscat1); 3-round shfl merge -> thr = 3rd-of-192 >= true d3 (subset).
// Phase B (2D): any candidate with e <= thr has |dx|,|dy| <= sqrt(thr) =>
//   inside bucket box [bxlo..bxhi]x[bylo..byhi] (+1 bucket margin >> ulp).
//   Rows (fixed y-bucket) are contiguous runs of kscat2; a query's 8 lanes
//   take rows round-robin (disjoint => no dedup); min-4 screen + u64
//   (f32bits<<32|idx) lex insert; thr tightens monotonically. Final 3-round
//   u64 shfl merge. Selection == lax.top_k bit-exact (tie -> lower idx).
__global__ __launch_bounds__(256) void knn10_kernel(
    const int* __restrict__ ucnt, const int* __restrict__ kbs1,
    const int* __restrict__ kbs2, const float4* __restrict__ qscat,
    const float4* __restrict__ scat1, const float4* __restrict__ scat2,
    int B, float* __restrict__ wgt, int* __restrict__ idxo)
{
    int tid = threadIdx.x;
    int wv = tid >> 6;
    int lane = tid & 63;
    int qi = lane & 7;           // query slot within wave
    int r8 = lane >> 3;          // private partition 0..7
    int pbase = blockIdx.x * 32;
    int qpos = pbase + wv * 8 + qi;

    int cum = 0, bb = 0;
    for (int i = 0; i < B; i++) { int c = ucnt[i]; if (qpos >= cum) bb = i; cum += c; }

    float4 qf = qscat[qpos];
    float ux = qf.x, uy = qf.y, uz = qf.z;

    int kst = kbs1[bb * NB];
    int ken = kbs1[bb * NB + NB];

    int bq = min(max((int)((ux - XMIN) * INVW), 0), NB - 1);
    int sp = kbs1[bb * NB + bq];

    int abase = sp - PA / 2;
    if (abase + PA > ken) abase = ken - PA;
    if (abase < kst) abase = kst;
    int aend = min(abase + PA, ken);

    // ---------------- phase A: own 24-candidate segment, value-only -------
    float d0 = INF, d1 = INF, d2v = INF;
    auto upd = [&](float e) {
        float m0 = fmaxf(e, d0), m1 = fmaxf(e, d1);
        d0 = fminf(e, d0); d1 = fminf(m0, d1); d2v = fminf(m1, d2v);
    };
    {
        int alo = abase + r8 * (PA / 8);
        int ahi = min(alo + PA / 8, aend);
        int i = alo;
        for (; i + 4 <= ahi; i += 4) {
            float e[4];
#pragma unroll
            for (int c = 0; c < 4; c++) {
                float4 f = scat1[i + c];
                float dx = f.x - ux, dy = f.y - uy, dz = f.z - uz;
                e[c] = __builtin_fmaf(dx, dx, __builtin_fmaf(dy, dy, dz * dz));
            }
#pragma unroll
            for (int c = 0; c < 4; c++) upd(e[c]);
        }
        for (; i < ahi; i++) {
            float4 f = scat1[i];
            float dx = f.x - ux, dy = f.y - uy, dz = f.z - uz;
            upd(__builtin_fmaf(dx, dx, __builtin_fmaf(dy, dy, dz * dz)));
        }
    }
#pragma unroll
    for (int s = 8; s <= 32; s <<= 1) {
        float e0 = __shfl_xor(d0, s, 64);
        float e1 = __shfl_xor(d1, s, 64);
        float e2 = __shfl_xor(d2v, s, 64);
        upd(e0); upd(e1); upd(e2);
    }
    float thr = d2v;

    // ---------------- phase B: 2D box, rows round-robin over lanes --------
    float Wr = fminf(sqrtf(thr), 300.0f);    // guard
    int bxlo = max((int)((ux - Wr - XMIN) * GIW) - 1, 0);
    int bxhi = min((int)((ux + Wr - XMIN) * GIW) + 1, NG - 1);
    int bylo = max((int)((uy - Wr - XMIN) * GIW) - 1, 0);
    int byhi = min((int)((uy + Wr - XMIN) * GIW) + 1, NG - 1);

    unsigned long long k0 = ~0ULL, k1 = ~0ULL, k2 = ~0ULL;
    auto insK = [&](unsigned long long k) {
        bool cc0 = k < k0;
        unsigned long long t0 = cc0 ? k : k0;
        unsigned long long t1 = cc0 ? k0 : k;
        bool cc1 = t1 < k1;
        unsigned long long u0 = cc1 ? t1 : k1;
        unsigned long long u1 = cc1 ? k1 : t1;
        k0 = t0; k1 = u0;
        k2 = u1 < k2 ? u1 : k2;
    };

    for (int ry = bylo + r8; ry <= byhi; ry += 8) {
        int rowb = bb * NG2 + ry * NG;
        int lo = kbs2[rowb + bxlo];
        int hi = kbs2[rowb + bxhi + 1];
        int i = lo;
        for (; i + 4 <= hi; i += 4) {
            float e[4]; int ix[4];
#pragma unroll
            for (int c = 0; c < 4; c++) {
                float4 f = scat2[i + c];
                float dx = f.x - ux, dy = f.y - uy, dz = f.z - uz;
                e[c] = __builtin_fmaf(dx, dx, __builtin_fmaf(dy, dy, dz * dz));
                ix[c] = __float_as_int(f.w);
            }
            float m4 = fminf(fminf(e[0], e[1]), fminf(e[2], e[3]));
            if (m4 <= thr) {
#pragma unroll
                for (int c = 0; c < 4; c++) {
                    if (e[c] <= thr) {
                        insK(((unsigned long long)__float_as_uint(e[c]) << 32) |
                             (unsigned)ix[c]);
                        thr = fminf(thr, __uint_as_float((unsigned)(k2 >> 32)));
                    }
                }
            }
        }
        for (; i < hi; i++) {
            float4 f = scat2[i];
            float dx = f.x - ux, dy = f.y - uy, dz = f.z - uz;
            float e = __builtin_fmaf(dx, dx, __builtin_fmaf(dy, dy, dz * dz));
            if (e <= thr) {
                insK(((unsigned long long)__float_as_uint(e) << 32) |
                     (unsigned)__float_as_int(f.w));
                thr = fminf(thr, __uint_as_float((unsigned)(k2 >> 32)));
            }
        }
    }

    // ---------------- final merge across the query's 8 lanes --------------
#pragma unroll
    for (int s = 8; s <= 32; s <<= 1) {
        unsigned long long e0 = shflx_u64(k0, s);
        unsigned long long e1 = shflx_u64(k1, s);
        unsigned long long e2 = shflx_u64(k2, s);
        insK(e0); insK(e1); insK(e2);
    }

    if (r8 == 0) {
        float dd0 = __uint_as_float((unsigned)(k0 >> 32));
        float dd1 = __uint_as_float((unsigned)(k1 >> 32));
        float dd2 = __uint_as_float((unsigned)(k2 >> 32));
        float r0 = 1.0f / (dd0 + 1e-8f);
        float r1 = 1.0f / (dd1 + 1e-8f);
        float r2 = 1.0f / (dd2 + 1e-8f);
        float rs = 1.0f / (r0 + r1 + r2);
        int orig = __float_as_int(qf.w);
        wgt[orig * 3 + 0] = r0 * rs;
        wgt[orig * 3 + 1] = r1 * rs;
        wgt[orig * 3 + 2] = r2 * rs;
        idxo[orig * 3 + 0] = (int)(unsigned)k0;
        idxo[orig * 3 + 1] = (int)(unsigned)k1;
        idxo[orig * 3 + 2] = (int)(unsigned)k2;
    }
}

// ------------------------------------------------ weight fp32->bf16 conv --
__global__ __launch_bounds__(256) void wconv_kernel(
    const float* __restrict__ W1, const float* __restrict__ W2,
    unsigned short* __restrict__ W1b, unsigned short* __restrict__ W2b,
    int n1, int n2)
{
    int i = blockIdx.x * 256 + threadIdx.x;
    if (i < n1) W1b[i] = f2bf(W1[i]);
    int j = i - n1;
    if (j >= 0 && j < n2) W2b[j] = f2bf(W2[j]);
}

// -------------------------------------------------------- bf16 MFMA GEMM --
// C[N,256] = A[N,K] x W[256,K]^T.  128x128 tile, BK=32, 16x16x32 MFMA.
// MODE 2 (gemm1): A materialized on the fly in staging (interp cols 0..255
//   gathered from kfeat via wgt/idx; ufeat cols 256..383). C stored as BF16
//   (h1) — BN1 stats come from fp32 accumulators, exact.
// MODE 1 (gemm2): A = relu(h1_bf16*scale+shift) -> bf16; scale/shift computed
//   in a 256-thread LDS prologue from raw BN sums (bn_finalize folded in).
//   C stored fp32 (h2).
// Fused epilogue: per-block column sum/sumsq of C -> global atomics.
template <int K, int MODE>
__global__ __launch_bounds__(256) void gemm_bf16_kernel(
    const void* __restrict__ Aa, const float* __restrict__ ufeat,
    const unsigned short* __restrict__ W,
    const float* __restrict__ wgt, const int* __restrict__ idxv,
    const float* __restrict__ bnsum, const float* __restrict__ bnsq,
    const float* __restrict__ bng, const float* __restrict__ bnb, float invN,
    void* __restrict__ Cv, float* __restrict__ gsum, float* __restrict__ gsq)
{
    __shared__ unsigned short As[128 * 40];
    __shared__ unsigned short Bs[128 * 40];
    __shared__ float colsum[128];
    __shared__ float colsq[128];
    __shared__ float sc[256], sh[256];

    int tid = threadIdx.x;
    int w = tid >> 6, lane = tid & 63;
    int r = w >> 1, cq = w & 1;
    int m16 = lane & 15, q = lane >> 4;
    int bm = blockIdx.x * 128, bn = blockIdx.y * 128;

    if (MODE == 1) {            // fold bn_finalize: per-channel scale/shift
        float mean = bnsum[tid] * invN;
        float var = bnsq[tid] * invN - mean * mean;
        float scv = bng[tid] * rsqrtf(var + BN_EPS);
        sc[tid] = scv;
        sh[tid] = bnb[tid] - mean * scv;
    }

    // per-thread staging slots: rows srow, srow+64 with fixed 8-ch chunk kc
    int srow = tid >> 2;
    int kc = (tid & 3) * 8;
    float w0a[2], w1a[2], w2a[2];
    int j0a[2], j1a[2], j2a[2];
    if (MODE == 2) {
#pragma unroll
        for (int t = 0; t < 2; t++) {
            int pp = bm + srow + 64 * t;
            w0a[t] = wgt[pp * 3 + 0]; w1a[t] = wgt[pp * 3 + 1]; w2a[t] = wgt[pp * 3 + 2];
            j0a[t] = idxv[pp * 3 + 0]; j1a[t] = idxv[pp * 3 + 1]; j2a[t] = idxv[pp * 3 + 2];
        }
    }

    f32x4 acc[4][4];
#pragma unroll
    for (int i = 0; i < 4; i++)
#pragma unroll
        for (int j = 0; j < 4; j++) acc[i][j] = (f32x4){0.f, 0.f, 0.f, 0.f};

#pragma unroll
    for (int k0 = 0; k0 < K; k0 += 32) {
        __syncthreads();
#pragma unroll
        for (int t = 0; t < 2; t++) {
            int row = srow + 64 * t;
            int c = k0 + kc;
            ushort4 o0, o1;
            if (MODE == 2) {
                if (c < 256) {          // interp cols (compile-time per iter)
                    const float* f0 = (const float*)Aa + (size_t)j0a[t] * 256 + c;
                    const float* f1 = (const float*)Aa + (size_t)j1a[t] * 256 + c;
                    const float* f2 = (const float*)Aa + (size_t)j2a[t] * 256 + c;
                    float4 x0 = *(const float4*)f0, x1 = *(const float4*)(f0 + 4);
                    float4 y0 = *(const float4*)f1, y1 = *(const float4*)(f1 + 4);
                    float4 z0 = *(const float4*)f2, z1 = *(const float4*)(f2 + 4);
                    float W0 = w0a[t], W1 = w1a[t], W2 = w2a[t];
                    o0.x = f2bf(x0.x * W0 + y0.x * W1 + z0.x * W2);
                    o0.y = f2bf(x0.y * W0 + y0.y * W1 + z0.y * W2);
                    o0.z = f2bf(x0.z * W0 + y0.z * W1 + z0.z * W2);
                    o0.w = f2bf(x0.w * W0 + y0.w * W1 + z0.w * W2);
                    o1.x = f2bf(x1.x * W0 + y1.x * W1 + z1.x * W2);
                    o1.y = f2bf(x1.y * W0 + y1.y * W1 + z1.y * W2);
                    o1.z = f2bf(x1.z * W0 + y1.z * W1 + z1.z * W2);
                    o1.w = f2bf(x1.w * W0 + y1.w * W1 + z1.w * W2);
                } else {                // ufeat cols
                    const float* fu = ufeat + (size_t)(bm + row) * 128 + (c - 256);
                    float4 u0 = *(const float4*)fu, u1 = *(const float4*)(fu + 4);
                    o0.x = f2bf(u0.x); o0.y = f2bf(u0.y);
                    o0.z = f2bf(u0.z); o0.w = f2bf(u0.w);
                    o1.x = f2bf(u1.x); o1.y = f2bf(u1.y);
                    o1.z = f2bf(u1.z); o1.w = f2bf(u1.w);
                }
            } else {                    // MODE 1: bn+relu+bf16 from bf16 h1
                const unsigned short* Ab = (const unsigned short*)Aa;
                ushort4 h0 = *(const ushort4*)(Ab + (size_t)(bm + row) * K + c);
                ushort4 h1v = *(const ushort4*)(Ab + (size_t)(bm + row) * K + c + 4);
                float4 s0 = *(const float4*)&sc[c];
                float4 s1 = *(const float4*)&sc[c + 4];
                float4 t0 = *(const float4*)&sh[c];
                float4 t1 = *(const float4*)&sh[c + 4];
                o0.x = f2bf(fmaxf(bf2f(h0.x) * s0.x + t0.x, 0.f));
                o0.y = f2bf(fmaxf(bf2f(h0.y) * s0.y + t0.y, 0.f));
                o0.z = f2bf(fmaxf(bf2f(h0.z) * s0.z + t0.z, 0.f));
                o0.w = f2bf(fmaxf(bf2f(h0.w) * s0.w + t0.w, 0.f));
                o1.x = f2bf(fmaxf(bf2f(h1v.x) * s1.x + t1.x, 0.f));
                o1.y = f2bf(fmaxf(bf2f(h1v.y) * s1.y + t1.y, 0.f));
                o1.z = f2bf(fmaxf(bf2f(h1v.z) * s1.z + t1.z, 0.f));
                o1.w = f2bf(fmaxf(bf2f(h1v.w) * s1.w + t1.w, 0.f));
            }
            *(ushort4*)&As[row * 40 + kc] = o0;
            *(ushort4*)&As[row * 40 + kc + 4] = o1;
            *(short8*)&Bs[row * 40 + kc] =
                *(const short8*)(W + (size_t)(bn + row) * K + k0 + kc);
        }
        __syncthreads();

        short8 af[4], bf[4];
#pragma unroll
        for (int sub = 0; sub < 4; sub++) {
            af[sub] = *(const short8*)&As[(r * 64 + sub * 16 + m16) * 40 + q * 8];
            bf[sub] = *(const short8*)&Bs[(cq * 64 + sub * 16 + m16) * 40 + q * 8];
        }
#pragma unroll
        for (int sm = 0; sm < 4; sm++)
#pragma unroll
            for (int sn = 0; sn < 4; sn++)
                acc[sm][sn] = __builtin_amdgcn_mfma_f32_16x16x32_bf16(
                    af[sm], bf[sn], acc[sm][sn], 0, 0, 0);
    }

    int row0 = bm + r * 64 + q * 4;
    int col0 = bn + cq * 64 + m16;
#pragma unroll
    for (int sm = 0; sm < 4; sm++)
#pragma unroll
        for (int sn = 0; sn < 4; sn++) {
            f32x4 v = acc[sm][sn];
#pragma unroll
            for (int reg = 0; reg < 4; reg++) {
                size_t idx = (size_t)(row0 + sm * 16 + reg) * 256 + col0 + sn * 16;
                if (MODE == 2) ((unsigned short*)Cv)[idx] = f2bf(v[reg]);
                else           ((float*)Cv)[idx] = v[reg];
            }
        }

    // ---- fused BN stats: per-block column sums of the 128x128 C tile ----
    __syncthreads();
    if (tid < 128) { colsum[tid] = 0.f; colsq[tid] = 0.f; }
    __syncthreads();
#pragma unroll
    for (int sn = 0; sn < 4; sn++) {
        float sacc = 0.f, qacc = 0.f;
#pragma unroll
        for (int sm = 0; sm < 4; sm++) {
            f32x4 v = acc[sm][sn];
#pragma unroll
            for (int reg = 0; reg < 4; reg++) {
                sacc += v[reg];
                qacc += v[reg] * v[reg];
            }
        }
        int lc = cq * 64 + sn * 16 + m16;
        atomicAdd(&colsum[lc], sacc);
        atomicAdd(&colsq[lc], qacc);
    }
    __syncthreads();
    if (tid < 128) {
        atomicAdd(&gsum[bn + tid], colsum[tid]);
        atomicAdd(&gsq[bn + tid], colsq[tid]);
    }
}

// --------- final: h2(ws) -> bn(raw sums, folded finalize)+relu -> d_out ---
__global__ __launch_bounds__(256) void final_act_kernel(
    const float* __restrict__ h2, const float* __restrict__ bnsum,
    const float* __restrict__ bnsq, const float* __restrict__ bng,
    const float* __restrict__ bnb, float invN,
    float* __restrict__ out, int total4)
{
    __shared__ float sc[256], sh[256];
    int c = threadIdx.x;
    float mean = bnsum[c] * invN;
    float var = bnsq[c] * invN - mean * mean;
    float scv = bng[c] * rsqrtf(var + BN_EPS);
    sc[c] = scv;
    sh[c] = bnb[c] - mean * scv;
    __syncthreads();

    int i = blockIdx.x * 256 + threadIdx.x;
    if (i >= total4) return;
    int c4 = i & 63;
    float4 v = ((const float4*)h2)[i];
    float4 s = *(const float4*)&sc[c4 * 4];
    float4 t = *(const float4*)&sh[c4 * 4];
    float4 o;
    o.x = fmaxf(v.x * s.x + t.x, 0.0f);
    o.y = fmaxf(v.y * s.y + t.y, 0.0f);
    o.z = fmaxf(v.z * s.z + t.z, 0.0f);
    o.w = fmaxf(v.w * s.w + t.w, 0.0f);
    ((float4*)out)[i] = o;
}

// ------------------------------------------------------------------ launch --
extern "C" void kernel_launch(void* const* d_in, const int* in_sizes, int n_in,
                              void* d_out, int out_size, void* d_ws, size_t ws_size,
                              hipStream_t stream)
{
    const float* unknown = (const float*)d_in[0];
    const int*   ucnt    = (const int*)d_in[1];
    const float* known   = (const float*)d_in[2];
    const int*   kcnt    = (const int*)d_in[3];
    const float* ufeat   = (const float*)d_in[4];
    const float* kfeat   = (const float*)d_in[5];
    const float* W1      = (const float*)d_in[6];
    const float* g1      = (const float*)d_in[7];
    const float* b1      = (const float*)d_in[8];
    const float* W2      = (const float*)d_in[9];
    const float* g2      = (const float*)d_in[10];
    const float* b2      = (const float*)d_in[11];

    int N = in_sizes[0] / 3;        // 65536
    int B = in_sizes[1];            // 4
    int M = in_sizes[2] / 3;        // 16384
    int T1 = B * NB;                // 4096
    int T2 = B * NG2;               // 16384

    char* ws = (char*)d_ws;
    size_t off = 0;
    float* wgt = (float*)(ws + off);            off += (size_t)N * 3 * 4;
    int*   idxb = (int*)(ws + off);             off += (size_t)N * 3 * 4;
    float* stats = (float*)(ws + off);          off += 4 * 256 * 4;
    float* sum1 = stats,        *sq1 = stats + 256;
    float* sum2 = stats + 512,  *sq2 = stats + 768;
    // histograms directly after stats -> one memset covers stats+kc1+kc2+qc2
    int* kc1 = (int*)(ws + off);                off += (size_t)T1 * 4;
    int* kc2 = (int*)(ws + off);                off += (size_t)T2 * 4;
    int* qc2 = (int*)(ws + off);                off += (size_t)T2 * 4;
    int* kbs1 = (int*)(ws + off);               off += ((size_t)T1 + 1) * 4;
    int* kbs2 = (int*)(ws + off);               off += ((size_t)T2 + 1) * 4;
    int* qbs2 = (int*)(ws + off);               off += ((size_t)T2 + 1) * 4;
    int* kcur1 = (int*)(ws + off);              off += (size_t)T1 * 4;
    int* kcur2 = (int*)(ws + off);              off += (size_t)T2 * 4;
    int* qcur2 = (int*)(ws + off);              off += (size_t)T2 * 4;
    unsigned short* W1b = (unsigned short*)(ws + off);  off += 256 * 384 * 2;
    unsigned short* W2b = (unsigned short*)(ws + off);  off += 256 * 256 * 2;
    off = (off + 255) & ~(size_t)255;
    float4* kscat1 = (float4*)(ws + off);       off += (size_t)M * sizeof(float4);
    float4* kscat2 = (float4*)(ws + off);       off += (size_t)M * sizeof(float4);
    float4* qscat = (float4*)(ws + off);        off += (size_t)N * sizeof(float4);
    off = (off + 255) & ~(size_t)255;
    unsigned short* h1 = (unsigned short*)(ws + off);   off += (size_t)N * 256 * 2;
    off = (off + 255) & ~(size_t)255;
    float* h2 = (float*)(ws + off);             // N*256 fp32 (67MB)

    float invN = 1.0f / (float)N;

    hipMemsetAsync(stats, 0, 4 * 256 * 4 + ((size_t)T1 + 2 * (size_t)T2) * 4,
                   stream);

    wconv_kernel<<<(256 * 384 + 256 * 256 + 255) / 256, 256, 0, stream>>>(
        W1, W2, W1b, W2b, 256 * 384, 256 * 256);

    hist3_kernel<<<(M + N + 255) / 256, 256, 0, stream>>>(
        known, kcnt, M, unknown, ucnt, N, B, kc1, kc2, qc2);
    scan3_kernel<<<3, 1024, 0, stream>>>(kc1, kbs1, kcur1, kc2, kbs2, kcur2,
                                         qc2, qbs2, qcur2, T1, T2);
    scatter3_kernel<<<(M + N + 255) / 256, 256, 0, stream>>>(
        known, kcnt, M, unknown, ucnt, N, B,
        kcur1, kscat1, kcur2, kscat2, qcur2, qscat);
    knn10_kernel<<<N / 32, 256, 0, stream>>>(ucnt, kbs1, kbs2, qscat,
                                             kscat1, kscat2, B, wgt, idxb);

    gemm_bf16_kernel<384, 2><<<dim3(N / 128, 2), 256, 0, stream>>>(
        kfeat, ufeat, W1b, wgt, idxb,
        nullptr, nullptr, nullptr, nullptr, 0.f, h1, sum1, sq1);
    gemm_bf16_kernel<256, 1><<<dim3(N / 128, 2), 256, 0, stream>>>(
        h1, nullptr, W2b, nullptr, nullptr,
        sum1, sq1, g1, b1, invN, h2, sum2, sq2);
    final_act_kernel<<<N / 4, 256, 0, stream>>>(h2, sum2, sq2, g2, b2, invN,
                                                (float*)d_out, N * 64);
}

// Round 11
// 357.214 us; speedup vs baseline: 1.1456x; 1.1456x over previous
//
#include <hip/hip_runtime.h>
#include <math.h>

typedef __attribute__((ext_vector_type(8))) short short8;
typedef __attribute__((ext_vector_type(4))) float f32x4;

#define INF 3.0e38f
#define BN_EPS 1e-5f

// ---- x-bucket grid for 3-NN (exact; per-query windowed scan) ------------
#define NB 1024            // buckets per batch along x
#define XMIN (-64.0f)
#define INVW 8.0f          // 1/0.125 bucket width
#define PA 192             // phase-A x-nearest per query (24 per lane)

__device__ __forceinline__ unsigned short f2bf(float x) {
    union { float f; unsigned u; } v; v.f = x;
    unsigned r = v.u + 0x7FFF + ((v.u >> 16) & 1);   // RNE
    return (unsigned short)(r >> 16);
}
__device__ __forceinline__ float bf2f(unsigned short u) {
    return __uint_as_float(((unsigned)u) << 16);
}
__device__ __forceinline__ unsigned long long shflx_u64(unsigned long long v, int m) {
    int lo = __shfl_xor((int)(unsigned)(v & 0xFFFFFFFFULL), m, 64);
    int hi = __shfl_xor((int)(unsigned)(v >> 32), m, 64);
    return ((unsigned long long)(unsigned)hi << 32) | (unsigned)lo;
}

// ------------------------------------------------- grid: fused histogram --
__global__ __launch_bounds__(256) void hist2_kernel(
    const float* __restrict__ kn, const int* __restrict__ kcnt, int M,
    const float* __restrict__ un, const int* __restrict__ ucnt, int N,
    int B, int* __restrict__ kc, int* __restrict__ qc)
{
    int j = blockIdx.x * 256 + threadIdx.x;
    const float* P; const int* C; int* out; int idx;
    if (j < M) { P = kn; C = kcnt; out = kc; idx = j; }
    else { idx = j - M; if (idx >= N) return; P = un; C = ucnt; out = qc; }
    int cum = 0, bb = 0;
    for (int i = 0; i < B; i++) { int c = C[i]; if (idx >= cum) bb = i; cum += c; }
    float x = P[idx * 3];
    int bi = (int)((x - XMIN) * INVW);
    bi = min(max(bi, 0), NB - 1);
    atomicAdd(&out[bb * NB + bi], 1);
}

// ------------------------- grid: exclusive scans (block 0: known, 1: unk) --
__global__ __launch_bounds__(1024) void scan2_kernel(
    const int* __restrict__ kc, int* __restrict__ kbs, int* __restrict__ kcur,
    const int* __restrict__ qc, int* __restrict__ qbs, int* __restrict__ qcur,
    int T)
{
    __shared__ int ts[1024];
    const int* cnt = blockIdx.x ? qc : kc;
    int* bs  = blockIdx.x ? qbs : kbs;
    int* cur = blockIdx.x ? qcur : kcur;

    int tid = threadIdx.x;
    int base = tid * 4;
    int v0 = 0, v1 = 0, v2 = 0, v3 = 0;
    if (base + 0 < T) v0 = cnt[base + 0];
    if (base + 1 < T) v1 = cnt[base + 1];
    if (base + 2 < T) v2 = cnt[base + 2];
    if (base + 3 < T) v3 = cnt[base + 3];
    int s = v0 + v1 + v2 + v3;
    ts[tid] = s;
    __syncthreads();
    for (int off = 1; off < 1024; off <<= 1) {
        int t = (tid >= off) ? ts[tid - off] : 0;
        __syncthreads();
        ts[tid] += t;
        __syncthreads();
    }
    int ex = ts[tid] - s;
    if (base + 0 < T) { bs[base + 0] = ex; cur[base + 0] = ex; } ex += v0;
    if (base + 1 < T) { bs[base + 1] = ex; cur[base + 1] = ex; } ex += v1;
    if (base + 2 < T) { bs[base + 2] = ex; cur[base + 2] = ex; } ex += v2;
    if (base + 3 < T) { bs[base + 3] = ex; cur[base + 3] = ex; } ex += v3;
    if (tid == ((T - 1) >> 2)) bs[T] = ts[tid];
}

// --------------------------------------------------- grid: fused scatter --
__global__ __launch_bounds__(256) void scatter2_kernel(
    const float* __restrict__ kn, const int* __restrict__ kcnt, int M,
    const float* __restrict__ un, const int* __restrict__ ucnt, int N,
    int B, int* __restrict__ kcur, float4* __restrict__ kscat,
    int* __restrict__ qcur, float4* __restrict__ qscat)
{
    int j = blockIdx.x * 256 + threadIdx.x;
    const float* P; const int* C; int* cur; float4* out; int idx;
    if (j < M) { P = kn; C = kcnt; cur = kcur; out = kscat; idx = j; }
    else { idx = j - M; if (idx >= N) return; P = un; C = ucnt; cur = qcur; out = qscat; }
    int cum = 0, bb = 0;
    for (int i = 0; i < B; i++) { int c = C[i]; if (idx >= cum) bb = i; cum += c; }
    float x = P[idx * 3], y = P[idx * 3 + 1], z = P[idx * 3 + 2];
    int bi = (int)((x - XMIN) * INVW);
    bi = min(max(bi, 0), NB - 1);
    int pos = atomicAdd(&cur[bb * NB + bi], 1);
    out[pos] = make_float4(x, y, z, __int_as_float(idx));
}

// ---------------------------------------------------------------- 3-NN ----
// Wave = 8 queries x 8 lanes, lane = qi*8 + r8 (qi = lane>>3 query slot,
// r8 = lane&7 partition residue). COALESCED PARTITIONS: each query's 8
// ADJACENT lanes take a stride-8 interleave of its window, so one load
// instruction reads 8 consecutive float4s (128B) per query (~16 cachelines
// per wave-instruction vs ~64 with R6/R9's contiguous-eighth split, which
// left the kernel VMEM-transaction bound at VALUBusy 42%).
// STRATIFIED BALANCE (R9): qpos = (qi>>1)*(N/4) + w*2 + (qi&1).
// No LDS, no __syncthreads; cross-lane traffic via shfl_xor(1/2/4).
// Phase A: value-only top-3 over own residue of the query's 192 x-nearest;
//   3-round shfl merge -> thr = 3rd-of-192 >= true d3 (subset bound).
// Window: buckets within +-sqrt(thr) (+1 bucket margin >> sqrtf ulp); any
//   excluded candidate has |dx| > sqrt(thr) => e > thr >= d3 (strict).
// Phase B: residues mod 8 are disjoint and cover the window; 8 loads in
//   flight (two min-4 screens) + u64 (f32bits<<32|idx) lex insert; thr
//   tightens monotonically (screen-out => e > current-3rd >= final-3rd).
//   Final 3-round u64 shfl merge, no dedup. Selection == lax.top_k
//   bit-exact (ties -> lower global idx), order-independent.
__global__ __launch_bounds__(256) void knn11_kernel(
    const int* __restrict__ ucnt, const int* __restrict__ kbs,
    const float4* __restrict__ qscat, const float4* __restrict__ scat,
    int B, int N, float* __restrict__ wgt, int* __restrict__ idxo)
{
    int tid = threadIdx.x;
    int wv = tid >> 6;
    int lane = tid & 63;
    int qi = lane >> 3;          // query slot within wave (adjacent lanes!)
    int r8 = lane & 7;           // partition residue 0..7
    int w = blockIdx.x * 4 + wv;             // global wave id, [0, N/8)
    int qpos = (qi >> 1) * (N >> 2) + w * 2 + (qi & 1);   // stratified

    int cum = 0, bb = 0;
    for (int i = 0; i < B; i++) { int c = ucnt[i]; if (qpos >= cum) bb = i; cum += c; }

    float4 qf = qscat[qpos];
    float ux = qf.x, uy = qf.y, uz = qf.z;

    int kst = kbs[bb * NB];
    int ken = kbs[bb * NB + NB];

    int bq = (int)((ux - XMIN) * INVW);
    bq = min(max(bq, 0), NB - 1);
    int sp = kbs[bb * NB + bq];

    int abase = sp - PA / 2;
    if (abase + PA > ken) abase = ken - PA;
    if (abase < kst) abase = kst;
    int aend = min(abase + PA, ken);

    // ------- phase A: stride-8 interleave of [abase, aend), value-only ----
    float d0 = INF, d1 = INF, d2v = INF;
    auto upd = [&](float e) {
        float m0 = fmaxf(e, d0), m1 = fmaxf(e, d1);
        d0 = fminf(e, d0); d1 = fminf(m0, d1); d2v = fminf(m1, d2v);
    };
    {
        int i = abase + r8;
        for (; i + 24 < aend; i += 32) {     // 4 loads: i, i+8, i+16, i+24
            float e[4];
#pragma unroll
            for (int c = 0; c < 4; c++) {
                float4 f = scat[i + 8 * c];
                float dx = f.x - ux, dy = f.y - uy, dz = f.z - uz;
                e[c] = __builtin_fmaf(dx, dx, __builtin_fmaf(dy, dy, dz * dz));
            }
#pragma unroll
            for (int c = 0; c < 4; c++) upd(e[c]);
        }
        for (; i < aend; i += 8) {
            float4 f = scat[i];
            float dx = f.x - ux, dy = f.y - uy, dz = f.z - uz;
            upd(__builtin_fmaf(dx, dx, __builtin_fmaf(dy, dy, dz * dz)));
        }
    }
    // merge values across the query's 8 adjacent lanes (xor 1, 2, 4)
#pragma unroll
    for (int s = 1; s <= 4; s <<= 1) {
        float e0 = __shfl_xor(d0, s, 64);
        float e1 = __shfl_xor(d1, s, 64);
        float e2 = __shfl_xor(d2v, s, 64);
        upd(e0); upd(e1); upd(e2);
    }
    float thr = d2v;

    // ---------------- per-query window ------------------------------------
    float Wr = fminf(sqrtf(thr), 300.0f);    // guard INF
    int blo = max((int)((ux - Wr - XMIN) * INVW) - 1, 0);
    int bhi = min((int)((ux + Wr - XMIN) * INVW) + 1, NB - 1);
    int pLo = kbs[bb * NB + blo];
    int pHi = kbs[bb * NB + bhi + 1];

    // ------- phase B: stride-8 interleave, screened u64 top-3 -------------
    unsigned long long k0 = ~0ULL, k1 = ~0ULL, k2 = ~0ULL;
    auto insK = [&](unsigned long long k) {
        bool cc0 = k < k0;
        unsigned long long t0 = cc0 ? k : k0;
        unsigned long long t1 = cc0 ? k0 : k;
        bool cc1 = t1 < k1;
        unsigned long long u0 = cc1 ? t1 : k1;
        unsigned long long u1 = cc1 ? k1 : t1;
        k0 = t0; k1 = u0;
        k2 = u1 < k2 ? u1 : k2;
    };

    int i = pLo + r8;
    for (; i + 56 < pHi; i += 64) {          // 8 loads: i, i+8, ..., i+56
        float e[8]; int ix[8];
#pragma unroll
        for (int c = 0; c < 8; c++) {
            float4 f = scat[i + 8 * c];
            float dx = f.x - ux, dy = f.y - uy, dz = f.z - uz;
            e[c] = __builtin_fmaf(dx, dx, __builtin_fmaf(dy, dy, dz * dz));
            ix[c] = __float_as_int(f.w);
        }
        float m4a = fminf(fminf(e[0], e[1]), fminf(e[2], e[3]));
        float m4b = fminf(fminf(e[4], e[5]), fminf(e[6], e[7]));
        if (m4a <= thr) {
#pragma unroll
            for (int c = 0; c < 4; c++) {
                if (e[c] <= thr) {
                    insK(((unsigned long long)__float_as_uint(e[c]) << 32) |
                         (unsigned)ix[c]);
                    thr = fminf(thr, __uint_as_float((unsigned)(k2 >> 32)));
                }
            }
        }
        if (m4b <= thr) {
#pragma unroll
            for (int c = 4; c < 8; c++) {
                if (e[c] <= thr) {
                    insK(((unsigned long long)__float_as_uint(e[c]) << 32) |
                         (unsigned)ix[c]);
                    thr = fminf(thr, __uint_as_float((unsigned)(k2 >> 32)));
                }
            }
        }
    }
    for (; i < pHi; i += 8) {
        float4 f = scat[i];
        float dx = f.x - ux, dy = f.y - uy, dz = f.z - uz;
        float e = __builtin_fmaf(dx, dx, __builtin_fmaf(dy, dy, dz * dz));
        if (e <= thr) {
            insK(((unsigned long long)__float_as_uint(e) << 32) |
                 (unsigned)__float_as_int(f.w));
            thr = fminf(thr, __uint_as_float((unsigned)(k2 >> 32)));
        }
    }

    // -------- final merge across the query's 8 adjacent lanes -------------
#pragma unroll
    for (int s = 1; s <= 4; s <<= 1) {
        unsigned long long e0 = shflx_u64(k0, s);
        unsigned long long e1 = shflx_u64(k1, s);
        unsigned long long e2 = shflx_u64(k2, s);
        insK(e0); insK(e1); insK(e2);
    }

    if (r8 == 0) {
        float dd0 = __uint_as_float((unsigned)(k0 >> 32));
        float dd1 = __uint_as_float((unsigned)(k1 >> 32));
        float dd2 = __uint_as_float((unsigned)(k2 >> 32));
        float r0 = 1.0f / (dd0 + 1e-8f);
        float r1 = 1.0f / (dd1 + 1e-8f);
        float r2 = 1.0f / (dd2 + 1e-8f);
        float rs = 1.0f / (r0 + r1 + r2);
        int orig = __float_as_int(qf.w);
        wgt[orig * 3 + 0] = r0 * rs;
        wgt[orig * 3 + 1] = r1 * rs;
        wgt[orig * 3 + 2] = r2 * rs;
        idxo[orig * 3 + 0] = (int)(unsigned)k0;
        idxo[orig * 3 + 1] = (int)(unsigned)k1;
        idxo[orig * 3 + 2] = (int)(unsigned)k2;
    }
}

// ------------------------------------------------ weight fp32->bf16 conv --
__global__ __launch_bounds__(256) void wconv_kernel(
    const float* __restrict__ W1, const float* __restrict__ W2,
    unsigned short* __restrict__ W1b, unsigned short* __restrict__ W2b,
    int n1, int n2)
{
    int i = blockIdx.x * 256 + threadIdx.x;
    if (i < n1) W1b[i] = f2bf(W1[i]);
    int j = i - n1;
    if (j >= 0 && j < n2) W2b[j] = f2bf(W2[j]);
}

// -------------------------------------------------------- bf16 MFMA GEMM --
// C[N,256] = A[N,K] x W[256,K]^T.  128x128 tile, BK=32, 16x16x32 MFMA.
// MODE 2 (gemm1): A materialized on the fly in staging (interp cols 0..255
//   gathered from kfeat via wgt/idx; ufeat cols 256..383). C stored as BF16
//   (h1) — BN1 stats come from fp32 accumulators, exact.
// MODE 1 (gemm2): A = relu(h1_bf16*scale+shift) -> bf16; scale/shift computed
//   in a 256-thread LDS prologue from raw BN sums (bn_finalize folded in).
//   C stored fp32 (h2).
// Fused epilogue: per-block column sum/sumsq of C -> global atomics.
template <int K, int MODE>
__global__ __launch_bounds__(256) void gemm_bf16_kernel(
    const void* __restrict__ Aa, const float* __restrict__ ufeat,
    const unsigned short* __restrict__ W,
    const float* __restrict__ wgt, const int* __restrict__ idxv,
    const float* __restrict__ bnsum, const float* __restrict__ bnsq,
    const float* __restrict__ bng, const float* __restrict__ bnb, float invN,
    void* __restrict__ Cv, float* __restrict__ gsum, float* __restrict__ gsq)
{
    __shared__ unsigned short As[128 * 40];
    __shared__ unsigned short Bs[128 * 40];
    __shared__ float colsum[128];
    __shared__ float colsq[128];
    __shared__ float sc[256], sh[256];

    int tid = threadIdx.x;
    int w = tid >> 6, lane = tid & 63;
    int r = w >> 1, cq = w & 1;
    int m16 = lane & 15, q = lane >> 4;
    int bm = blockIdx.x * 128, bn = blockIdx.y * 128;

    if (MODE == 1) {            // fold bn_finalize: per-channel scale/shift
        float mean = bnsum[tid] * invN;
        float var = bnsq[tid] * invN - mean * mean;
        float scv = bng[tid] * rsqrtf(var + BN_EPS);
        sc[tid] = scv;
        sh[tid] = bnb[tid] - mean * scv;
    }

    // per-thread staging slots: rows srow, srow+64 with fixed 8-ch chunk kc
    int srow = tid >> 2;
    int kc = (tid & 3) * 8;
    float w0a[2], w1a[2], w2a[2];
    int j0a[2], j1a[2], j2a[2];
    if (MODE == 2) {
#pragma unroll
        for (int t = 0; t < 2; t++) {
            int pp = bm + srow + 64 * t;
            w0a[t] = wgt[pp * 3 + 0]; w1a[t] = wgt[pp * 3 + 1]; w2a[t] = wgt[pp * 3 + 2];
            j0a[t] = idxv[pp * 3 + 0]; j1a[t] = idxv[pp * 3 + 1]; j2a[t] = idxv[pp * 3 + 2];
        }
    }

    f32x4 acc[4][4];
#pragma unroll
    for (int i = 0; i < 4; i++)
#pragma unroll
        for (int j = 0; j < 4; j++) acc[i][j] = (f32x4){0.f, 0.f, 0.f, 0.f};

#pragma unroll
    for (int k0 = 0; k0 < K; k0 += 32) {
        __syncthreads();
#pragma unroll
        for (int t = 0; t < 2; t++) {
            int row = srow + 64 * t;
            int c = k0 + kc;
            ushort4 o0, o1;
            if (MODE == 2) {
                if (c < 256) {          // interp cols (compile-time per iter)
                    const float* f0 = (const float*)Aa + (size_t)j0a[t] * 256 + c;
                    const float* f1 = (const float*)Aa + (size_t)j1a[t] * 256 + c;
                    const float* f2 = (const float*)Aa + (size_t)j2a[t] * 256 + c;
                    float4 x0 = *(const float4*)f0, x1 = *(const float4*)(f0 + 4);
                    float4 y0 = *(const float4*)f1, y1 = *(const float4*)(f1 + 4);
                    float4 z0 = *(const float4*)f2, z1 = *(const float4*)(f2 + 4);
                    float W0 = w0a[t], W1 = w1a[t], W2 = w2a[t];
                    o0.x = f2bf(x0.x * W0 + y0.x * W1 + z0.x * W2);
                    o0.y = f2bf(x0.y * W0 + y0.y * W1 + z0.y * W2);
                    o0.z = f2bf(x0.z * W0 + y0.z * W1 + z0.z * W2);
                    o0.w = f2bf(x0.w * W0 + y0.w * W1 + z0.w * W2);
                    o1.x = f2bf(x1.x * W0 + y1.x * W1 + z1.x * W2);
                    o1.y = f2bf(x1.y * W0 + y1.y * W1 + z1.y * W2);
                    o1.z = f2bf(x1.z * W0 + y1.z * W1 + z1.z * W2);
                    o1.w = f2bf(x1.w * W0 + y1.w * W1 + z1.w * W2);
                } else {                // ufeat cols
                    const float* fu = ufeat + (size_t)(bm + row) * 128 + (c - 256);
                    float4 u0 = *(const float4*)fu, u1 = *(const float4*)(fu + 4);
                    o0.x = f2bf(u0.x); o0.y = f2bf(u0.y);
                    o0.z = f2bf(u0.z); o0.w = f2bf(u0.w);
                    o1.x = f2bf(u1.x); o1.y = f2bf(u1.y);
                    o1.z = f2bf(u1.z); o1.w = f2bf(u1.w);
                }
            } else {                    // MODE 1: bn+relu+bf16 from bf16 h1
                const unsigned short* Ab = (const unsigned short*)Aa;
                ushort4 h0 = *(const ushort4*)(Ab + (size_t)(bm + row) * K + c);
                ushort4 h1v = *(const ushort4*)(Ab + (size_t)(bm + row) * K + c + 4);
                float4 s0 = *(const float4*)&sc[c];
                float4 s1 = *(const float4*)&sc[c + 4];
                float4 t0 = *(const float4*)&sh[c];
                float4 t1 = *(const float4*)&sh[c + 4];
                o0.x = f2bf(fmaxf(bf2f(h0.x) * s0.x + t0.x, 0.f));
                o0.y = f2bf(fmaxf(bf2f(h0.y) * s0.y + t0.y, 0.f));
                o0.z = f2bf(fmaxf(bf2f(h0.z) * s0.z + t0.z, 0.f));
                o0.w = f2bf(fmaxf(bf2f(h0.w) * s0.w + t0.w, 0.f));
                o1.x = f2bf(fmaxf(bf2f(h1v.x) * s1.x + t1.x, 0.f));
                o1.y = f2bf(fmaxf(bf2f(h1v.y) * s1.y + t1.y, 0.f));
                o1.z = f2bf(fmaxf(bf2f(h1v.z) * s1.z + t1.z, 0.f));
                o1.w = f2bf(fmaxf(bf2f(h1v.w) * s1.w + t1.w, 0.f));
            }
            *(ushort4*)&As[row * 40 + kc] = o0;
            *(ushort4*)&As[row * 40 + kc + 4] = o1;
            *(short8*)&Bs[row * 40 + kc] =
                *(const short8*)(W + (size_t)(bn + row) * K + k0 + kc);
        }
        __syncthreads();

        short8 af[4], bf[4];
#pragma unroll
        for (int sub = 0; sub < 4; sub++) {
            af[sub] = *(const short8*)&As[(r * 64 + sub * 16 + m16) * 40 + q * 8];
            bf[sub] = *(const short8*)&Bs[(cq * 64 + sub * 16 + m16) * 40 + q * 8];
        }
#pragma unroll
        for (int sm = 0; sm < 4; sm++)
#pragma unroll
            for (int sn = 0; sn < 4; sn++)
                acc[sm][sn] = __builtin_amdgcn_mfma_f32_16x16x32_bf16(
                    af[sm], bf[sn], acc[sm][sn], 0, 0, 0);
    }

    int row0 = bm + r * 64 + q * 4;
    int col0 = bn + cq * 64 + m16;
#pragma unroll
    for (int sm = 0; sm < 4; sm++)
#pragma unroll
        for (int sn = 0; sn < 4; sn++) {
            f32x4 v = acc[sm][sn];
#pragma unroll
            for (int reg = 0; reg < 4; reg++) {
                size_t idx = (size_t)(row0 + sm * 16 + reg) * 256 + col0 + sn * 16;
                if (MODE == 2) ((unsigned short*)Cv)[idx] = f2bf(v[reg]);
                else           ((float*)Cv)[idx] = v[reg];
            }
        }

    // ---- fused BN stats: per-block column sums of the 128x128 C tile ----
    __syncthreads();
    if (tid < 128) { colsum[tid] = 0.f; colsq[tid] = 0.f; }
    __syncthreads();
#pragma unroll
    for (int sn = 0; sn < 4; sn++) {
        float sacc = 0.f, qacc = 0.f;
#pragma unroll
        for (int sm = 0; sm < 4; sm++) {
            f32x4 v = acc[sm][sn];
#pragma unroll
            for (int reg = 0; reg < 4; reg++) {
                sacc += v[reg];
                qacc += v[reg] * v[reg];
            }
        }
        int lc = cq * 64 + sn * 16 + m16;
        atomicAdd(&colsum[lc], sacc);
        atomicAdd(&colsq[lc], qacc);
    }
    __syncthreads();
    if (tid < 128) {
        atomicAdd(&gsum[bn + tid], colsum[tid]);
        atomicAdd(&gsq[bn + tid], colsq[tid]);
    }
}

// --------- final: h2(ws) -> bn(raw sums, folded finalize)+relu -> d_out ---
__global__ __launch_bounds__(256) void final_act_kernel(
    const float* __restrict__ h2, const float* __restrict__ bnsum,
    const float* __restrict__ bnsq, const float* __restrict__ bng,
    const float* __restrict__ bnb, float invN,
    float* __restrict__ out, int total4)
{
    __shared__ float sc[256], sh[256];
    int c = threadIdx.x;
    float mean = bnsum[c] * invN;
    float var = bnsq[c] * invN - mean * mean;
    float scv = bng[c] * rsqrtf(var + BN_EPS);
    sc[c] = scv;
    sh[c] = bnb[c] - mean * scv;
    __syncthreads();

    int i = blockIdx.x * 256 + threadIdx.x;
    if (i >= total4) return;
    int c4 = i & 63;
    float4 v = ((const float4*)h2)[i];
    float4 s = *(const float4*)&sc[c4 * 4];
    float4 t = *(const float4*)&sh[c4 * 4];
    float4 o;
    o.x = fmaxf(v.x * s.x + t.x, 0.0f);
    o.y = fmaxf(v.y * s.y + t.y, 0.0f);
    o.z = fmaxf(v.z * s.z + t.z, 0.0f);
    o.w = fmaxf(v.w * s.w + t.w, 0.0f);
    ((float4*)out)[i] = o;
}

// ------------------------------------------------------------------ launch --
extern "C" void kernel_launch(void* const* d_in, const int* in_sizes, int n_in,
                              void* d_out, int out_size, void* d_ws, size_t ws_size,
                              hipStream_t stream)
{
    const float* unknown = (const float*)d_in[0];
    const int*   ucnt    = (const int*)d_in[1];
    const float* known   = (const float*)d_in[2];
    const int*   kcnt    = (const int*)d_in[3];
    const float* ufeat   = (const float*)d_in[4];
    const float* kfeat   = (const float*)d_in[5];
    const float* W1      = (const float*)d_in[6];
    const float* g1      = (const float*)d_in[7];
    const float* b1      = (const float*)d_in[8];
    const float* W2      = (const float*)d_in[9];
    const float* g2      = (const float*)d_in[10];
    const float* b2      = (const float*)d_in[11];

    int N = in_sizes[0] / 3;        // 65536
    int B = in_sizes[1];            // 4
    int M = in_sizes[2] / 3;        // 16384
    int T = B * NB;

    char* ws = (char*)d_ws;
    size_t off = 0;
    float* wgt = (float*)(ws + off);            off += (size_t)N * 3 * 4;
    int*   idxb = (int*)(ws + off);             off += (size_t)N * 3 * 4;
    float* stats = (float*)(ws + off);          off += 4 * 256 * 4;
    float* sum1 = stats,        *sq1 = stats + 256;
    float* sum2 = stats + 512,  *sq2 = stats + 768;
    // histograms directly after stats -> one memset covers stats+kch+qch
    int* kch = (int*)(ws + off);                off += (size_t)T * 4;
    int* qch = (int*)(ws + off);                off += (size_t)T * 4;
    int* kbs = (int*)(ws + off);                off += ((size_t)T + 1) * 4;
    int* qbs = (int*)(ws + off);                off += ((size_t)T + 1) * 4;
    int* kcur = (int*)(ws + off);               off += (size_t)T * 4;
    int* qcur = (int*)(ws + off);               off += (size_t)T * 4;
    unsigned short* W1b = (unsigned short*)(ws + off);  off += 256 * 384 * 2;
    unsigned short* W2b = (unsigned short*)(ws + off);  off += 256 * 256 * 2;
    off = (off + 255) & ~(size_t)255;
    float4* kscat = (float4*)(ws + off);        off += (size_t)M * sizeof(float4);
    float4* qscat = (float4*)(ws + off);        off += (size_t)N * sizeof(float4);
    off = (off + 255) & ~(size_t)255;
    unsigned short* h1 = (unsigned short*)(ws + off);   off += (size_t)N * 256 * 2;
    off = (off + 255) & ~(size_t)255;
    float* h2 = (float*)(ws + off);             // N*256 fp32 (67MB)

    float invN = 1.0f / (float)N;

    hipMemsetAsync(stats, 0, 4 * 256 * 4 + 2 * (size_t)T * 4, stream);

    wconv_kernel<<<(256 * 384 + 256 * 256 + 255) / 256, 256, 0, stream>>>(
        W1, W2, W1b, W2b, 256 * 384, 256 * 256);

    hist2_kernel<<<(M + N + 255) / 256, 256, 0, stream>>>(
        known, kcnt, M, unknown, ucnt, N, B, kch, qch);
    scan2_kernel<<<2, 1024, 0, stream>>>(kch, kbs, kcur, qch, qbs, qcur, T);
    scatter2_kernel<<<(M + N + 255) / 256, 256, 0, stream>>>(
        known, kcnt, M, unknown, ucnt, N, B, kcur, kscat, qcur, qscat);
    knn11_kernel<<<N / 32, 256, 0, stream>>>(ucnt, kbs, qscat, kscat,
                                             B, N, wgt, idxb);

    gemm_bf16_kernel<384, 2><<<dim3(N / 128, 2), 256, 0, stream>>>(
        kfeat, ufeat, W1b, wgt, idxb,
        nullptr, nullptr, nullptr, nullptr, 0.f, h1, sum1, sq1);
    gemm_bf16_kernel<256, 1><<<dim3(N / 128, 2), 256, 0, stream>>>(
        h1, nullptr, W2b, nullptr, nullptr,
        sum1, sq1, g1, b1, invN, h2, sum2, sq2);
    final_act_kernel<<<N / 4, 256, 0, stream>>>(h2, sum2, sq2, g2, b2, invN,
                                                (float*)d_out, N * 64);
}